// Round 1
// baseline (12830.794 us; speedup 1.0000x reference)
//
#include <hip/hip_runtime.h>
#include <math.h>

// MinimalRNN: S=256 steps, B=256 batch, H=1024, L=3 layers.
// y[t] = h_2(t), h_N = h_l(255).  out = [y (S*B*H) | h_N (L*B*H)] fp32.
//
// Round-1 design: 192 persistent WGs (3 layers x 2 row-blocks x 32 col-blocks),
// 256 threads each, 1 WG/CU (128 KiB LDS).  Each WG owns a [128 x 32] output
// slice of its layer; weight slice [32 x 2048] lives in LDS as fp16 in MFMA
// B-fragment order.  Activations ring-buffered (depth 4) in ws as fp16;
// producer/consumer sync via per-(layer,t) counters with agent-scope atomics
// (cross-XCD safe).  Compute: v_mfma_f32_16x16x32_f16, fp32 accum, fp32 tanh.

#define S_LEN  256
#define BATCH  256
#define HID    1024
#define NLAY   3
#define RING   4
#define COLS   32
#define ROWS   128
#define WG_PER_LAYER 64   // 2 row-blocks * 32 col-blocks
#define TOTAL_WG     192
#define THREADS      256

typedef _Float16 v8h __attribute__((ext_vector_type(8)));
typedef float    v4f __attribute__((ext_vector_type(4)));

#define MFMA16(a, b, c) __builtin_amdgcn_mfma_f32_16x16x32_f16((a), (b), (c), 0, 0, 0)

__device__ __forceinline__ void spin_wait(int* p, int target) {
  while (__hip_atomic_load(p, __ATOMIC_ACQUIRE, __HIP_MEMORY_SCOPE_AGENT) < target) {
    __builtin_amdgcn_s_sleep(1);
  }
}

// Pre-kernel: zero the done counters, seed ring slot (RING-1) with h_0.
// ws is re-poisoned 0xAA before every launch, so this must run every call.
__global__ void rnn_pre(const float* __restrict__ h0,
                        _Float16* __restrict__ hring,
                        int* __restrict__ done) {
  int idx = blockIdx.x * blockDim.x + threadIdx.x;
  if (idx < NLAY * S_LEN) done[idx] = 0;
  if (idx < NLAY * BATCH * HID) {
    int l   = idx / (BATCH * HID);
    int off = idx - l * (BATCH * HID);
    hring[(size_t)(l * RING + (RING - 1)) * BATCH * HID + off] = (_Float16)h0[idx];
  }
}

__global__ __launch_bounds__(THREADS, 1) void rnn_main(
    const float* __restrict__ x,
    const float* __restrict__ W_ih, const float* __restrict__ W_hh,
    const float* __restrict__ b_ih, const float* __restrict__ b_hh,
    float* __restrict__ out,
    _Float16* __restrict__ hring, int* __restrict__ done) {
  // B-fragment-swizzled weight slice: [kc 0..63][col-tile 0..1][lane][8 fp16]
  // kc*32 spans concatenated K: k<1024 -> W_ih, k>=1024 -> W_hh.
  __shared__ _Float16 WB[64][2][64][8];  // 128 KiB

  const int tid  = threadIdx.x;
  const int lane = tid & 63;
  const int wave = tid >> 6;
  const int wg   = blockIdx.x;
  const int l    = wg >> 6;   // 64 WGs per layer
  const int sub  = wg & 63;
  const int rb   = sub >> 5;  // row-block 0..1
  const int cb   = sub & 31;  // col-block 0..31

  // ---- one-time: stage weight slice into LDS (fp32 -> fp16, swizzled) ----
  for (int i = tid; i < 64 * 2 * 64; i += THREADS) {
    const int kc = i >> 7;
    const int ct = (i >> 6) & 1;
    const int ln = i & 63;
    const int c    = ct * 16 + (ln & 15);
    const int k0   = kc * 32 + ((ln >> 4) << 3);
    const int gcol = cb * COLS + c;
    const float* src = (k0 < HID)
        ? (W_ih + (size_t)l * HID * HID + (size_t)gcol * HID + k0)
        : (W_hh + (size_t)l * HID * HID + (size_t)gcol * HID + (k0 - HID));
    v8h w;
#pragma unroll
    for (int j = 0; j < 8; ++j) w[j] = (_Float16)src[j];
    *(v8h*)(&WB[kc][ct][ln][0]) = w;
  }

  const int   c0    = cb * COLS + (lane & 15);
  const float bias0 = b_ih[l * HID + c0]      + b_hh[l * HID + c0];
  const float bias1 = b_ih[l * HID + c0 + 16] + b_hh[l * HID + c0 + 16];
  __syncthreads();

  const int rowbase = rb * ROWS + wave * 32;  // this wave's 32 rows
  const int r0      = rowbase + (lane & 15);
  const int r1      = r0 + 16;
  const int kfrag   = (lane >> 4) << 3;       // quad*8

  int* const my_done = &done[l * S_LEN];

  for (int t = 0; t < S_LEN; ++t) {
    // ---- dependency waits (thread 0 spins, others park at barrier) ----
    if (tid == 0) {
      if (l > 0)                      spin_wait(&done[(l - 1) * S_LEN + t], WG_PER_LAYER);
      if (t > 0)                      spin_wait(&my_done[t - 1], WG_PER_LAYER);
      if (l < NLAY - 1 && t >= RING)  spin_wait(&done[(l + 1) * S_LEN + t - RING], WG_PER_LAYER);
    }
    __syncthreads();
    // Invalidate stale L1/L2 lines so ring reads see producers' data.
    __builtin_amdgcn_fence(__ATOMIC_ACQUIRE, "agent");

    v4f acc[2][2];
#pragma unroll
    for (int a = 0; a < 2; ++a)
#pragma unroll
      for (int b = 0; b < 2; ++b) acc[a][b] = (v4f){0.f, 0.f, 0.f, 0.f};

    // ---- GEMM part 1: inp @ W_ih^T  (K = 0..1023) ----
    if (l == 0) {
      const float* a0p = x + (size_t)t * BATCH * HID + (size_t)r0 * HID + kfrag;
      const float* a1p = a0p + (size_t)16 * HID;
#pragma unroll 4
      for (int kc = 0; kc < 32; ++kc) {
        v4f f0 = *(const v4f*)(a0p + kc * 32);
        v4f f1 = *(const v4f*)(a0p + kc * 32 + 4);
        v4f g0 = *(const v4f*)(a1p + kc * 32);
        v4f g1 = *(const v4f*)(a1p + kc * 32 + 4);
        v8h a0, a1;
#pragma unroll
        for (int j = 0; j < 4; ++j) {
          a0[j]     = (_Float16)f0[j];
          a0[j + 4] = (_Float16)f1[j];
          a1[j]     = (_Float16)g0[j];
          a1[j + 4] = (_Float16)g1[j];
        }
        v8h b0 = *(const v8h*)(&WB[kc][0][lane][0]);
        v8h b1 = *(const v8h*)(&WB[kc][1][lane][0]);
        acc[0][0] = MFMA16(a0, b0, acc[0][0]);
        acc[0][1] = MFMA16(a0, b1, acc[0][1]);
        acc[1][0] = MFMA16(a1, b0, acc[1][0]);
        acc[1][1] = MFMA16(a1, b1, acc[1][1]);
      }
    } else {
      const _Float16* base = hring + (size_t)((l - 1) * RING + (t & (RING - 1))) * BATCH * HID;
      const _Float16* a0p  = base + (size_t)r0 * HID + kfrag;
      const _Float16* a1p  = a0p + (size_t)16 * HID;
#pragma unroll 8
      for (int kc = 0; kc < 32; ++kc) {
        v8h a0 = *(const v8h*)(a0p + kc * 32);
        v8h a1 = *(const v8h*)(a1p + kc * 32);
        v8h b0 = *(const v8h*)(&WB[kc][0][lane][0]);
        v8h b1 = *(const v8h*)(&WB[kc][1][lane][0]);
        acc[0][0] = MFMA16(a0, b0, acc[0][0]);
        acc[0][1] = MFMA16(a0, b1, acc[0][1]);
        acc[1][0] = MFMA16(a1, b0, acc[1][0]);
        acc[1][1] = MFMA16(a1, b1, acc[1][1]);
      }
    }

    // ---- GEMM part 2: h_prev @ W_hh^T  (K = 1024..2047) ----
    {
      const _Float16* base = hring + (size_t)(l * RING + ((t + RING - 1) & (RING - 1))) * BATCH * HID;
      const _Float16* a0p  = base + (size_t)r0 * HID + kfrag;
      const _Float16* a1p  = a0p + (size_t)16 * HID;
#pragma unroll 8
      for (int kc = 0; kc < 32; ++kc) {
        v8h a0 = *(const v8h*)(a0p + kc * 32);
        v8h a1 = *(const v8h*)(a1p + kc * 32);
        v8h b0 = *(const v8h*)(&WB[kc + 32][0][lane][0]);
        v8h b1 = *(const v8h*)(&WB[kc + 32][1][lane][0]);
        acc[0][0] = MFMA16(a0, b0, acc[0][0]);
        acc[0][1] = MFMA16(a0, b1, acc[0][1]);
        acc[1][0] = MFMA16(a1, b0, acc[1][0]);
        acc[1][1] = MFMA16(a1, b1, acc[1][1]);
      }
    }

    // ---- epilogue: bias + tanh, write ring (fp16), y / h_N (fp32) ----
    // C/D layout: col = lane&15 (+16*ct), row = (lane>>4)*4 + reg (+16*rt).
    _Float16* hout = hring + (size_t)(l * RING + (t & (RING - 1))) * BATCH * HID;
    float*    yout = out + (size_t)t * BATCH * HID;
    float*    hN   = out + (size_t)S_LEN * BATCH * HID + (size_t)l * BATCH * HID;
    const int qrow = (lane >> 4) << 2;
    const int ccol = lane & 15;
#pragma unroll
    for (int rt = 0; rt < 2; ++rt) {
#pragma unroll
      for (int ct = 0; ct < 2; ++ct) {
        const float bb   = (ct == 0) ? bias0 : bias1;
        const int   colg = cb * COLS + ct * 16 + ccol;
#pragma unroll
        for (int i = 0; i < 4; ++i) {
          const int rowg = rowbase + rt * 16 + qrow + i;
          const float hv = tanhf(acc[rt][ct][i] + bb);
          hout[(size_t)rowg * HID + colg] = (_Float16)hv;
          if (l == NLAY - 1)  yout[(size_t)rowg * HID + colg] = hv;
          if (t == S_LEN - 1) hN[(size_t)rowg * HID + colg]   = hv;
        }
      }
    }

    // ---- publish: drain all waves' stores, then release-increment flag ----
    __syncthreads();
    if (tid == 0) {
      __hip_atomic_fetch_add(&my_done[t], 1, __ATOMIC_RELEASE, __HIP_MEMORY_SCOPE_AGENT);
    }
  }
}

extern "C" void kernel_launch(void* const* d_in, const int* in_sizes, int n_in,
                              void* d_out, int out_size, void* d_ws, size_t ws_size,
                              hipStream_t stream) {
  (void)in_sizes; (void)n_in; (void)out_size; (void)ws_size;
  const float* x    = (const float*)d_in[0];
  const float* h0   = (const float*)d_in[1];
  const float* W_ih = (const float*)d_in[2];
  const float* W_hh = (const float*)d_in[3];
  const float* b_ih = (const float*)d_in[4];
  const float* b_hh = (const float*)d_in[5];
  float* out = (float*)d_out;

  int*      done  = (int*)d_ws;                        // 768 counters
  _Float16* hring = (_Float16*)((char*)d_ws + 4096);   // L*RING*B*H fp16 = 6 MiB

  const int pre_blocks = (NLAY * BATCH * HID + THREADS - 1) / THREADS;  // 3072
  rnn_pre<<<pre_blocks, THREADS, 0, stream>>>(h0, hring, done);
  rnn_main<<<TOTAL_WG, THREADS, 0, stream>>>(x, W_ih, W_hh, b_ih, b_hh, out, hring, done);
}